// Round 13
// baseline (164.237 us; speedup 1.0000x reference)
//
#include <hip/hip_runtime.h>
#include <hip/hip_bf16.h>

typedef unsigned int uint;

#define T_STEPS 32

// ---- workspace dword offsets ----
#define OFF_WB    0        // 30720: GRU B-frags
#define OFF_PJB   30720    // 4096 : proj B-frags (waves 0-3)
#define OFF_D0B   34816    // 6144 : drift_w0 B-frags (8 slots x 3 kt)
#define OFF_D1B   40960    // 8192
#define OFF_D2B   49152    // 8192
#define OFF_G0B   57344    // 6144
#define OFF_G1B   63488    // 8192
#define OFF_W3B   71680    // 1024 : drift_w3 head (N pad 15->16)
#define OFF_G2B   72704    // 1024 : diff_w2 head

typedef _Float16 half8 __attribute__((ext_vector_type(8)));
typedef float    f32x4 __attribute__((ext_vector_type(4)));

union FB { uint4 u4; half8 h; };

__device__ inline uint pack2f(float a, float b) {
  _Float16 ha = (_Float16)a, hb = (_Float16)b;
  unsigned short ua, ub;
  __builtin_memcpy(&ua, &ha, 2);
  __builtin_memcpy(&ub, &hb, 2);
  return (uint)ua | ((uint)ub << 16);
}

// ---- fast activations: Pade(3/2) tanh + clamp, raw v_rcp ----
__device__ inline float rcpf(float x) {
#if __has_builtin(__builtin_amdgcn_rcpf)
  return __builtin_amdgcn_rcpf(x);
#else
  return 1.f / x;
#endif
}
__device__ inline float tanh_fast(float x) {
  float t = x * x;
  float num = x * (27.f + t);
  float den = fmaf(t, 9.f, 27.f);
  float r = num * rcpf(den);
  return fminf(1.f, fmaxf(-1.f, r));
}
__device__ inline float sigm(float x) { return fmaf(tanh_fast(0.5f * x), 0.5f, 0.5f); }
__device__ inline float silu_f(float x) { return x * sigm(x); }

__device__ inline float map89(const float* __restrict__ W, int u, int k) {
  if (k < 25) return W[u * 89 + k];
  if (k < 32) return 0.f;
  return W[u * 89 + k - 7];   // ctx part: 25 + (k-32)
}

// ======================= weight pre-pack =======================
__global__ __launch_bounds__(256) void prep_kernel(
    const float* __restrict__ wih, const float* __restrict__ whh,
    const float* __restrict__ pw,
    const float* __restrict__ dw0, const float* __restrict__ dw1,
    const float* __restrict__ dw2, const float* __restrict__ gw0,
    const float* __restrict__ gw1, const float* __restrict__ dw3,
    const float* __restrict__ gw2, uint* __restrict__ wsu) {
  int id = blockIdx.x * 256 + threadIdx.x;
  if (id < 30720) {
    int i = id & 3, l = (id >> 2) & 63, t3 = id >> 8;
    int kt = t3 % 5, wg = t3 / 5;
    int w = wg / 3, gi = wg % 3;
    int row = gi * 128 + w * 16 + (l & 15);
    int k = ((l >> 4) << 3) + i * 2;
    float a, b;
    if (kt == 0) {
      a = (k     < 25) ? wih[row * 25 + k]     : 0.f;
      b = (k + 1 < 25) ? wih[row * 25 + k + 1] : 0.f;
    } else {
      int kh = (kt - 1) * 32 + k;
      a = whh[row * 128 + kh];
      b = whh[row * 128 + kh + 1];
    }
    wsu[OFF_WB + id] = pack2f(a, b);
  } else if (id < 34816) {               // proj B-frags: (w*4+kt)
    int t = id - 30720;
    int i = t & 3, l = (t >> 2) & 63, wkt = t >> 8;
    int kt = wkt & 3, w = wkt >> 2;
    int u = w * 16 + (l & 15);
    int k = kt * 32 + ((l >> 4) << 3) + i * 2;
    wsu[OFF_PJB + t] = pack2f(pw[u * 128 + k], pw[u * 128 + k + 1]);
  } else if (id < 40960) {               // drift_w0 (89-in, 8 slots x 3 kt)
    int t = id - 34816;
    int i = t & 3, l = (t >> 2) & 63, wkt = t >> 8;
    int kt = wkt % 3, w = wkt / 3;
    int u = w * 16 + (l & 15);
    int k = kt * 32 + ((l >> 4) << 3) + i * 2;
    wsu[OFF_D0B + t] = pack2f(map89(dw0, u, k), map89(dw0, u, k + 1));
  } else if (id < 49152) {               // drift_w1
    int t = id - 40960;
    int i = t & 3, l = (t >> 2) & 63, wkt = t >> 8;
    int kt = wkt & 3, w = wkt >> 2;
    int u = w * 16 + (l & 15);
    int k = kt * 32 + ((l >> 4) << 3) + i * 2;
    wsu[OFF_D1B + t] = pack2f(dw1[u * 128 + k], dw1[u * 128 + k + 1]);
  } else if (id < 57344) {               // drift_w2
    int t = id - 49152;
    int i = t & 3, l = (t >> 2) & 63, wkt = t >> 8;
    int kt = wkt & 3, w = wkt >> 2;
    int u = w * 16 + (l & 15);
    int k = kt * 32 + ((l >> 4) << 3) + i * 2;
    wsu[OFF_D2B + t] = pack2f(dw2[u * 128 + k], dw2[u * 128 + k + 1]);
  } else if (id < 63488) {               // diff_w0 (89-in)
    int t = id - 57344;
    int i = t & 3, l = (t >> 2) & 63, wkt = t >> 8;
    int kt = wkt % 3, w = wkt / 3;
    int u = w * 16 + (l & 15);
    int k = kt * 32 + ((l >> 4) << 3) + i * 2;
    wsu[OFF_G0B + t] = pack2f(map89(gw0, u, k), map89(gw0, u, k + 1));
  } else if (id < 71680) {               // diff_w1
    int t = id - 63488;
    int i = t & 3, l = (t >> 2) & 63, wkt = t >> 8;
    int kt = wkt & 3, w = wkt >> 2;
    int u = w * 16 + (l & 15);
    int k = kt * 32 + ((l >> 4) << 3) + i * 2;
    wsu[OFF_G1B + t] = pack2f(gw1[u * 128 + k], gw1[u * 128 + k + 1]);
  } else if (id < 72704) {               // drift_w3 head (15 outs, pad 16)
    int t = id - 71680;
    int i = t & 3, l = (t >> 2) & 63, kt = t >> 8;
    int o = l & 15;
    int k = kt * 32 + ((l >> 4) << 3) + i * 2;
    float a = (o < 15) ? dw3[o * 128 + k]     : 0.f;
    float b = (o < 15) ? dw3[o * 128 + k + 1] : 0.f;
    wsu[OFF_W3B + t] = pack2f(a, b);
  } else if (id < 73728) {               // diff_w2 head
    int t = id - 72704;
    int i = t & 3, l = (t >> 2) & 63, kt = t >> 8;
    int o = l & 15;
    int k = kt * 32 + ((l >> 4) << 3) + i * 2;
    float a = (o < 15) ? gw2[o * 128 + k]     : 0.f;
    float b = (o < 15) ? gw2[o * 128 + k + 1] : 0.f;
    wsu[OFF_G2B + t] = pack2f(a, b);
  }
}

// MLP dual-slot phase: A-frags in LDS, B-frags in VGPRs.
template <int KT>
__device__ inline void mlp_pair(const _Float16* __restrict__ aA,
                                const FB* B0, const FB* B1,
                                float bias0, float bias1,
                                _Float16* __restrict__ outA,
                                int lm, int lq, int ubase) {
  f32x4 c0 = {0.f, 0.f, 0.f, 0.f}, c1 = {0.f, 0.f, 0.f, 0.f};
#pragma unroll
  for (int kt = 0; kt < KT; kt++) {
    half8 a = *(const half8*)(aA + ((kt * 4 + lq) * 16 + lm) * 8);
    c0 = __builtin_amdgcn_mfma_f32_16x16x32_f16(a, B0[kt].h, c0, 0, 0, 0);
    c1 = __builtin_amdgcn_mfma_f32_16x16x32_f16(a, B1[kt].h, c1, 0, 0, 0);
  }
  int u0 = ubase + lm, u1 = ubase + 16 + lm;
  int base0 = (u0 >> 3) * 128 + (u0 & 7);
  int base1 = (u1 >> 3) * 128 + (u1 & 7);
#pragma unroll
  for (int s = 0; s < 4; s++) {
    outA[base0 + (lq * 4 + s) * 8] = (_Float16)silu_f(c0[s] + bias0);
    outA[base1 + (lq * 4 + s) * 8] = (_Float16)silu_f(c1[s] + bias1);
  }
}

// Layer-0 with step-invariant ctx contribution pre-accumulated (C-operand).
__device__ inline void mlp_pair_pre(const _Float16* __restrict__ aA,
                                    const FB& B0k0, const FB& B1k0,
                                    f32x4 cc0, f32x4 cc1,
                                    float bias0, float bias1,
                                    _Float16* __restrict__ outA,
                                    int lm, int lq, int ubase) {
  half8 a = *(const half8*)(aA + ((0 * 4 + lq) * 16 + lm) * 8);  // sigma ktile
  f32x4 c0 = __builtin_amdgcn_mfma_f32_16x16x32_f16(a, B0k0.h, cc0, 0, 0, 0);
  f32x4 c1 = __builtin_amdgcn_mfma_f32_16x16x32_f16(a, B1k0.h, cc1, 0, 0, 0);
  int u0 = ubase + lm, u1 = ubase + 16 + lm;
  int base0 = (u0 >> 3) * 128 + (u0 & 7);
  int base1 = (u1 >> 3) * 128 + (u1 & 7);
#pragma unroll
  for (int s = 0; s < 4; s++) {
    outA[base0 + (lq * 4 + s) * 8] = (_Float16)silu_f(c0[s] + bias0);
    outA[base1 + (lq * 4 + s) * 8] = (_Float16)silu_f(c1[s] + bias1);
  }
}

__device__ inline f32x4 head4(const _Float16* __restrict__ aA, const FB* H,
                              int lm, int lq) {
  f32x4 c = {0.f, 0.f, 0.f, 0.f};
#pragma unroll
  for (int kt = 0; kt < 4; kt++) {
    half8 a = *(const half8*)(aA + ((kt * 4 + lq) * 16 + lm) * 8);
    c = __builtin_amdgcn_mfma_f32_16x16x32_f16(a, H[kt].h, c, 0, 0, 0);
  }
  return c;
}

// ---- 5x5 wave-parallel matmul via raw ds_bpermute (hoisted addresses) ----
__device__ inline float bpf(int addr, float v) {
  return __int_as_float(__builtin_amdgcn_ds_bpermute(addr, __float_as_int(v)));
}
__device__ inline float mm5b(int iA, int iB, float A, float B) {
  float c = 0.f;
#pragma unroll
  for (int k = 0; k < 5; k++)
    c = fmaf(bpf(iA + 4 * k, A), bpf(iB + 20 * k, B), c);
  return c;
}

#define NS_ITER do { \
  float P_  = mm5b(iA0, iB0, Zv, Yv); \
  float Tm_ = 1.5f * gdel - 0.5f * P_; \
  float Yn_ = mm5b(iA0, iB0, Yv, Tm_); \
  float Zn_ = mm5b(iA0, iB0, Tm_, Zv); \
  Yv = Yn_; Zv = Zn_; } while (0)

// ======================= fused GRU + SDE =======================
// grid 256 x 512; block owns 16 batch rows.
__global__ __launch_bounds__(512) void fused_kernel(
    const float* __restrict__ ctp, const float* __restrict__ dWp,
    const uint* __restrict__ wsu,
    const float* __restrict__ gbias, const float* __restrict__ gbn,
    const float* __restrict__ projb,
    const float* __restrict__ db0, const float* __restrict__ db1,
    const float* __restrict__ db2, const float* __restrict__ b3,
    const float* __restrict__ gb0, const float* __restrict__ gb1,
    const float* __restrict__ gb2, float* __restrict__ outp) {
  __shared__ __align__(16) _Float16 bigbuf[16384];           // 32KB: x2 / SDE bufs
  __shared__ __align__(16) _Float16 hf[2][4][4][16][8];      // 8KB dbuf h A-frags
  __shared__ float sig_s[16 * 28];
  __shared__ float coeff_s[256];
  __shared__ float coeff2_s[256];
  const int tid = threadIdx.x;
  const int rb = blockIdx.x * 16;
  uint* bigu = (uint*)bigbuf;

  // ---- stage symmetrized features as A-frags (x2 = bigbuf) ----
  for (int idx = tid; idx < T_STEPS * 16 * 16; idx += 512) {
    int k2 = idx & 15, r = (idx >> 4) & 15, t = idx >> 8;
    const float* base = ctp + ((rb + r) * T_STEPS + t) * 25;
    int k0 = 2 * k2;
    float v0 = 0.f, v1 = 0.f;
    if (k0 < 25)     { int i5 = k0 / 5,     j5 = k0 % 5;     v0 = 0.5f * (base[i5*5+j5] + base[j5*5+i5]); }
    if (k0 + 1 < 25) { int i5 = (k0+1) / 5, j5 = (k0+1) % 5; v1 = 0.5f * (base[i5*5+j5] + base[j5*5+i5]); }
    int q = k2 >> 2, jh = k2 & 3;
    bigu[((t * 4 + q) * 16 + r) * 4 + jh] = pack2f(v0, v1);
  }

  const int w = tid >> 6, l = tid & 63;
  const int lm = l & 15, lq = l >> 4;
  const int u = w * 16 + lm;
  const int ku = u >> 5, qu = (u >> 3) & 3, ju = u & 7;
  FB Bf[3][5];
  const uint4* wb4p = (const uint4*)(wsu + OFF_WB);
#pragma unroll
  for (int gi = 0; gi < 3; gi++)
#pragma unroll
    for (int kt = 0; kt < 5; kt++)
      Bf[gi][kt].u4 = wb4p[((w * 3 + gi) * 5 + kt) * 64 + l];
  const float br = gbias[u], bz = gbias[128 + u], bg = gbias[256 + u], bn = gbn[u];
  float hprev[4] = {0.f, 0.f, 0.f, 0.f};
  __syncthreads();

  // ---- GRU t-loop (1 barrier/step; x-part software-pipelined;
  //      h-MFMA as two 2-deep chains to shorten the dependence path) ----
  f32x4 z4 = {0.f, 0.f, 0.f, 0.f};
  half8 axn = *(const half8*)(bigbuf + ((0 * 4 + lq) * 16 + lm) * 8);
  f32x4 pxr = __builtin_amdgcn_mfma_f32_16x16x32_f16(axn, Bf[0][0].h, z4, 0, 0, 0);
  f32x4 pxz = __builtin_amdgcn_mfma_f32_16x16x32_f16(axn, Bf[1][0].h, z4, 0, 0, 0);
  f32x4 pxg = __builtin_amdgcn_mfma_f32_16x16x32_f16(axn, Bf[2][0].h, z4, 0, 0, 0);
  for (int t = 0; t < T_STEPS; t++) {
    f32x4 cr = pxr, cz = pxz, cgv = pxg;
    f32x4 ch = {0.f, 0.f, 0.f, 0.f};
    if (t > 0) {
      const int p = t & 1;
      half8 ah0 = *(const half8*)(&hf[p][0][lq][lm][0]);
      half8 ah1 = *(const half8*)(&hf[p][1][lq][lm][0]);
      half8 ah2 = *(const half8*)(&hf[p][2][lq][lm][0]);
      half8 ah3 = *(const half8*)(&hf[p][3][lq][lm][0]);
      f32x4 cr2, cz2, ch2;
      cr  = __builtin_amdgcn_mfma_f32_16x16x32_f16(ah0, Bf[0][1].h, cr,  0, 0, 0);
      cz  = __builtin_amdgcn_mfma_f32_16x16x32_f16(ah0, Bf[1][1].h, cz,  0, 0, 0);
      ch  = __builtin_amdgcn_mfma_f32_16x16x32_f16(ah0, Bf[2][1].h, ch,  0, 0, 0);
      cr2 = __builtin_amdgcn_mfma_f32_16x16x32_f16(ah2, Bf[0][3].h, z4,  0, 0, 0);
      cz2 = __builtin_amdgcn_mfma_f32_16x16x32_f16(ah2, Bf[1][3].h, z4,  0, 0, 0);
      ch2 = __builtin_amdgcn_mfma_f32_16x16x32_f16(ah2, Bf[2][3].h, z4,  0, 0, 0);
      cr  = __builtin_amdgcn_mfma_f32_16x16x32_f16(ah1, Bf[0][2].h, cr,  0, 0, 0);
      cz  = __builtin_amdgcn_mfma_f32_16x16x32_f16(ah1, Bf[1][2].h, cz,  0, 0, 0);
      ch  = __builtin_amdgcn_mfma_f32_16x16x32_f16(ah1, Bf[2][2].h, ch,  0, 0, 0);
      cr2 = __builtin_amdgcn_mfma_f32_16x16x32_f16(ah3, Bf[0][4].h, cr2, 0, 0, 0);
      cz2 = __builtin_amdgcn_mfma_f32_16x16x32_f16(ah3, Bf[1][4].h, cz2, 0, 0, 0);
      ch2 = __builtin_amdgcn_mfma_f32_16x16x32_f16(ah3, Bf[2][4].h, ch2, 0, 0, 0);
      cr += cr2; cz += cz2; ch += ch2;
    }
    if (t < T_STEPS - 1) {   // prefetch next step's x-part (independent of h)
      axn = *(const half8*)(bigbuf + (((t + 1) * 4 + lq) * 16 + lm) * 8);
      pxr = __builtin_amdgcn_mfma_f32_16x16x32_f16(axn, Bf[0][0].h, z4, 0, 0, 0);
      pxz = __builtin_amdgcn_mfma_f32_16x16x32_f16(axn, Bf[1][0].h, z4, 0, 0, 0);
      pxg = __builtin_amdgcn_mfma_f32_16x16x32_f16(axn, Bf[2][0].h, z4, 0, 0, 0);
    }
    const int wp = (t + 1) & 1;
#pragma unroll
    for (int s = 0; s < 4; s++) {
      float r = sigm(cr[s] + br);
      float z = sigm(cz[s] + bz);
      float g = tanh_fast(cgv[s] + bg + r * (ch[s] + bn));
      float hn = fmaf(z, hprev[s] - g, g);
      hprev[s] = hn;
      hf[wp][ku][qu][lq * 4 + s][ju] = (_Float16)hn;
    }
    __syncthreads();
  }

  // ---- SDE B-frag preload (registers), role-split ----
  const int role = w >> 2;                 // 0: drift (waves 0-3), 1: diff (4-7)
  const int wbq = w & 3;
  FB F0[2][3], F1[2][4], F2[2][4], Pf[4], Hf[4];
  {
    const uint4* p0 = (const uint4*)(wsu + (role ? OFF_G0B : OFF_D0B));
    const uint4* p1 = (const uint4*)(wsu + (role ? OFF_G1B : OFF_D1B));
    const uint4* p2 = (const uint4*)(wsu + (role ? OFF_G1B : OFF_D2B)); // diff: dummy
#pragma unroll
    for (int s = 0; s < 2; s++) {
      int slot = wbq * 2 + s;
#pragma unroll
      for (int kt = 0; kt < 3; kt++) F0[s][kt].u4 = p0[(slot * 3 + kt) * 64 + l];
#pragma unroll
      for (int kt = 0; kt < 4; kt++) {
        F1[s][kt].u4 = p1[(slot * 4 + kt) * 64 + l];
        F2[s][kt].u4 = p2[(slot * 4 + kt) * 64 + l];
      }
    }
  }
  if (w < 4) {
#pragma unroll
    for (int kt = 0; kt < 4; kt++)
      Pf[kt].u4 = ((const uint4*)(wsu + OFF_PJB))[(w * 4 + kt) * 64 + l];
  }
  if (w == 0) {
#pragma unroll
    for (int kt = 0; kt < 4; kt++)
      Hf[kt].u4 = ((const uint4*)(wsu + OFF_W3B))[kt * 64 + l];
  } else if (w == 4) {
#pragma unroll
    for (int kt = 0; kt < 4; kt++)
      Hf[kt].u4 = ((const uint4*)(wsu + OFF_G2B))[kt * 64 + l];
  }
  float b0s[2], b1s[2], b2s[2];
#pragma unroll
  for (int s = 0; s < 2; s++) {
    int us = wbq * 32 + s * 16 + lm;
    b0s[s] = role ? gb0[us] : db0[us];
    b1s[s] = role ? gb1[us] : db1[us];
    b2s[s] = role ? 0.f : db2[us];
  }
  const int oc = (lm < 15) ? lm : 0;
  const float hb = (w == 0) ? b3[oc] : ((w == 4) ? gb2[oc] : 0.f);

  // prefetch ALL steps' dW (wave 4 only) so no vmem is outstanding at barriers
  float dwa[5][4];
  if (w == 4) {
#pragma unroll
    for (int st = 0; st < 5; st++)
#pragma unroll
      for (int s = 0; s < 4; s++)
        dwa[st][s] = dWp[((rb + lq * 4 + s) * 5 + st) * 15 + oc];
  }

  _Float16* inpA = bigbuf;          // 3 ktiles (k: 0-24 sigma | pad | 32-95 ctx)
  _Float16* bufA = bigbuf + 1536;   // drift d0 out / d2 out
  _Float16* bufB = bigbuf + 3584;   // diff g0 out
  _Float16* bufC = bigbuf + 5632;   // drift d1 out
  _Float16* bufD = bigbuf + 7680;   // diff g1 out

  // proj via MFMA (waves 0-3): ctx -> inpA ctx part
  if (w < 4) {
    f32x4 c = {0.f, 0.f, 0.f, 0.f};
#pragma unroll
    for (int kt = 0; kt < 4; kt++) {
      half8 a = *(const half8*)(&hf[0][kt][lq][lm][0]);
      c = __builtin_amdgcn_mfma_f32_16x16x32_f16(a, Pf[kt].h, c, 0, 0, 0);
    }
    const float pbv = projb[u];
    int kk = 32 + u, base = (kk >> 3) * 128 + (kk & 7);
#pragma unroll
    for (int s = 0; s < 4; s++)
      inpA[base + (lq * 4 + s) * 8] = (_Float16)(c[s] + pbv);
  }
  // sigma init + pad
  for (int idx = tid; idx < 400; idx += 512) {
    int e = idx / 25, k = idx % 25;
    int i5 = k / 5, j5 = k % 5;
    const float* base = ctp + ((rb + e) * T_STEPS + 31) * 25;
    float v = 0.5f * (base[i5 * 5 + j5] + base[j5 * 5 + i5]);
    sig_s[e * 28 + k] = v;
    inpA[(k >> 3) * 128 + e * 8 + (k & 7)] = (_Float16)v;
  }
  if (tid < 112) {
    int e = tid / 7, p = 25 + tid % 7;
    inpA[(p >> 3) * 128 + e * 8 + (p & 7)] = (_Float16)0.f;
  }
  // geometry lane constants
  const int ge = tid >> 5, glane = tid & 31;
  const int gli = (glane < 25) ? glane : 0;
  const int gii = gli / 5, gjj = gli % 5;
  const float gdel = (gii == gjj) ? 1.f : 0.f;
  const int gbase = (l & 32) << 2;
  const int iA0 = gbase + gii * 20;
  const int iB0 = gbase + gjj * 4;
  const int iT0 = gbase + (gjj * 5 + gii) * 4;
  __syncthreads();

  // step-invariant ctx contribution to layer0 (ktiles 1-2), both slots
  f32x4 cc0 = {0.f, 0.f, 0.f, 0.f}, cc1 = {0.f, 0.f, 0.f, 0.f};
#pragma unroll
  for (int kt = 1; kt < 3; kt++) {
    half8 a = *(const half8*)(inpA + ((kt * 4 + lq) * 16 + lm) * 8);
    cc0 = __builtin_amdgcn_mfma_f32_16x16x32_f16(a, F0[0][kt].h, cc0, 0, 0, 0);
    cc1 = __builtin_amdgcn_mfma_f32_16x16x32_f16(a, F0[1][kt].h, cc1, 0, 0, 0);
  }

  // ---- SDE step loop: 5 barriers/step; sqrt = cheb4 + NS1 + NS2 ----
  for (int st = 0; st < 5; st++) {
    float S = sig_s[ge * 28 + gli];
    float tr = 0.f;
#pragma unroll
    for (int d = 0; d < 5; d++) tr += bpf(gbase + 24 * d, S);
    const float That = S * (2.298851f / tr) - 1.068966f * gdel;
    float Yv, Zv;
    // p1: d0 || g0 (sigma ktile only; ctx pre-accumulated) + cheb4
    mlp_pair_pre(inpA, F0[0][0], F0[1][0], cc0, cc1, b0s[0], b0s[1],
                 role ? bufB : bufA, lm, lq, wbq * 32);
    {
      float T2 = mm5b(iA0, iB0, That, That);
      float X  = -1.13859f * That + 0.9901f * T2;
      float Zp = mm5b(iA0, iB0, T2, X)
               + 1.03702f * gdel - 0.21179f * That + 0.09756f * T2;
      Zv = Zp;
      float TZ = mm5b(iA0, iB0, That, Zp);
      Yv = 0.87f * TZ + 0.93f * Zp;
    }
    __syncthreads();
    // p2: d1 || g1  (+ NS1)
    mlp_pair<4>(role ? bufB : bufA, F1[0], F1[1], b1s[0], b1s[1],
                role ? bufD : bufC, lm, lq, wbq * 32);
    NS_ITER;
    __syncthreads();
    // p3: d2 || diff-head  (+ NS2)
    if (!role) {
      mlp_pair<4>(bufC, F2[0], F2[1], b2s[0], b2s[1], bufA, lm, lq, wbq * 32);
    } else if (w == 4) {
      f32x4 c = head4(bufD, Hf, lm, lq);
      if (lm < 15) {
#pragma unroll
        for (int s = 0; s < 4; s++) {
          float acc = c[s] + hb;
          float sp = (acc > 20.f) ? acc : __logf(1.f + __expf(acc));
          coeff2_s[(lq * 4 + s) * 16 + lm] = sp * dwa[st][s];
        }
      }
    }
    NS_ITER;
    __syncthreads();
    // p4: drift head; finalize L
    if (w == 0) {
      f32x4 c = head4(bufA, Hf, lm, lq);
      if (lm < 15) {
#pragma unroll
        for (int s = 0; s < 4; s++)
          coeff_s[(lq * 4 + s) * 16 + lm] = 0.2f * (c[s] + hb);
      }
    }
    float L = Yv * sqrtf(0.5f * tr);
    __syncthreads();
    // p5: tangent build + expm (deg-4 powers) + exp-map + write
    {
      float av;
      if (gii == gjj) av = coeff_s[ge * 16 + gii] + coeff2_s[ge * 16 + gii];
      else {
        int p = gii < gjj ? gii : gjj, qq = gii < gjj ? gjj : gii;
        int i5 = 5 + (p * (9 - p)) / 2 + (qq - p - 1);
        av = (coeff_s[ge * 16 + i5] + coeff2_s[ge * 16 + i5]) * 0.70710678f;
      }
      float a2 = mm5b(iA0, iB0, av, av);
      float X2 = 0.5f * gdel + av * 0.16666667f + a2 * 0.04166667f;
      float M = gdel + av + mm5b(iA0, iB0, a2, X2);
      float P2 = mm5b(iA0, iB0, L, M);
      float S2 = mm5b(iA0, iB0, P2, L);
      S2 = 0.5f * (S2 + bpf(iT0, S2));
      if (glane < 25) {
        sig_s[ge * 28 + gli] = S2;
        inpA[(gli >> 3) * 128 + ge * 8 + (gli & 7)] = (_Float16)S2;
      }
    }
    __syncthreads();
  }

  for (int idx = tid; idx < 400; idx += 512) {
    int e = idx / 25, k = idx % 25;
    outp[(rb + e) * 25 + k] = sig_s[e * 28 + k];
  }
}

extern "C" void kernel_launch(void* const* d_in, const int* in_sizes, int n_in,
                              void* d_out, int out_size, void* d_ws, size_t ws_size,
                              hipStream_t stream) {
  const float* ctp = (const float*)d_in[0];
  const float* dWp = (const float*)d_in[1];
  const float* wih = (const float*)d_in[2];
  const float* whh = (const float*)d_in[3];
  const float* gb  = (const float*)d_in[4];
  const float* gbn = (const float*)d_in[5];
  const float* pw  = (const float*)d_in[6];
  const float* pb  = (const float*)d_in[7];
  const float* dw0 = (const float*)d_in[8];
  const float* db0 = (const float*)d_in[9];
  const float* dw1 = (const float*)d_in[10];
  const float* db1 = (const float*)d_in[11];
  const float* dw2 = (const float*)d_in[12];
  const float* db2 = (const float*)d_in[13];
  const float* dw3 = (const float*)d_in[14];
  const float* db3 = (const float*)d_in[15];
  const float* gw0 = (const float*)d_in[16];
  const float* gb0 = (const float*)d_in[17];
  const float* gw1 = (const float*)d_in[18];
  const float* gb1 = (const float*)d_in[19];
  const float* gw2 = (const float*)d_in[20];
  const float* gb2 = (const float*)d_in[21];
  uint* wsu = (uint*)d_ws;

  hipLaunchKernelGGL(prep_kernel, dim3(288), dim3(256), 0, stream,
                     wih, whh, pw, dw0, dw1, dw2, gw0, gw1, dw3, gw2, wsu);
  hipLaunchKernelGGL(fused_kernel, dim3(256), dim3(512), 0, stream,
                     ctp, dWp, wsu, gb, gbn, pb,
                     db0, db1, db2, db3, gb0, gb1, gb2, (float*)d_out);
}

// Round 14
// 162.649 us; speedup vs baseline: 1.0098x; 1.0098x over previous
//
#include <hip/hip_runtime.h>
#include <hip/hip_bf16.h>

typedef unsigned int uint;

#define T_STEPS 32

// ---- workspace dword offsets ----
#define OFF_WB    0        // 30720: GRU B-frags
#define OFF_PJB   30720    // 4096 : proj B-frags (waves 0-3)
#define OFF_D0B   34816    // 6144 : drift_w0 B-frags (8 slots x 3 kt)
#define OFF_D1B   40960    // 8192
#define OFF_D2B   49152    // 8192
#define OFF_G0B   57344    // 6144
#define OFF_G1B   63488    // 8192
#define OFF_W3B   71680    // 1024 : drift_w3 head (N pad 15->16)
#define OFF_G2B   72704    // 1024 : diff_w2 head

typedef _Float16 half8 __attribute__((ext_vector_type(8)));
typedef float    f32x4 __attribute__((ext_vector_type(4)));

union FB { uint4 u4; half8 h; };

__device__ inline uint pack2f(float a, float b) {
  _Float16 ha = (_Float16)a, hb = (_Float16)b;
  unsigned short ua, ub;
  __builtin_memcpy(&ua, &ha, 2);
  __builtin_memcpy(&ub, &hb, 2);
  return (uint)ua | ((uint)ub << 16);
}

// ---- fast activations: Pade(3/2) tanh + clamp, raw v_rcp ----
__device__ inline float rcpf(float x) {
#if __has_builtin(__builtin_amdgcn_rcpf)
  return __builtin_amdgcn_rcpf(x);
#else
  return 1.f / x;
#endif
}
__device__ inline float tanh_fast(float x) {
  float t = x * x;
  float num = x * (27.f + t);
  float den = fmaf(t, 9.f, 27.f);
  float r = num * rcpf(den);
  return fminf(1.f, fmaxf(-1.f, r));
}
__device__ inline float sigm(float x) { return fmaf(tanh_fast(0.5f * x), 0.5f, 0.5f); }
__device__ inline float silu_f(float x) { return x * sigm(x); }

__device__ inline float map89(const float* __restrict__ W, int u, int k) {
  if (k < 25) return W[u * 89 + k];
  if (k < 32) return 0.f;
  return W[u * 89 + k - 7];   // ctx part: 25 + (k-32)
}

// ======================= weight pre-pack =======================
__global__ __launch_bounds__(256) void prep_kernel(
    const float* __restrict__ wih, const float* __restrict__ whh,
    const float* __restrict__ pw,
    const float* __restrict__ dw0, const float* __restrict__ dw1,
    const float* __restrict__ dw2, const float* __restrict__ gw0,
    const float* __restrict__ gw1, const float* __restrict__ dw3,
    const float* __restrict__ gw2, uint* __restrict__ wsu) {
  int id = blockIdx.x * 256 + threadIdx.x;
  if (id < 30720) {
    int i = id & 3, l = (id >> 2) & 63, t3 = id >> 8;
    int kt = t3 % 5, wg = t3 / 5;
    int w = wg / 3, gi = wg % 3;
    int row = gi * 128 + w * 16 + (l & 15);
    int k = ((l >> 4) << 3) + i * 2;
    float a, b;
    if (kt == 0) {
      a = (k     < 25) ? wih[row * 25 + k]     : 0.f;
      b = (k + 1 < 25) ? wih[row * 25 + k + 1] : 0.f;
    } else {
      int kh = (kt - 1) * 32 + k;
      a = whh[row * 128 + kh];
      b = whh[row * 128 + kh + 1];
    }
    wsu[OFF_WB + id] = pack2f(a, b);
  } else if (id < 34816) {               // proj B-frags: (w*4+kt)
    int t = id - 30720;
    int i = t & 3, l = (t >> 2) & 63, wkt = t >> 8;
    int kt = wkt & 3, w = wkt >> 2;
    int u = w * 16 + (l & 15);
    int k = kt * 32 + ((l >> 4) << 3) + i * 2;
    wsu[OFF_PJB + t] = pack2f(pw[u * 128 + k], pw[u * 128 + k + 1]);
  } else if (id < 40960) {               // drift_w0 (89-in, 8 slots x 3 kt)
    int t = id - 34816;
    int i = t & 3, l = (t >> 2) & 63, wkt = t >> 8;
    int kt = wkt % 3, w = wkt / 3;
    int u = w * 16 + (l & 15);
    int k = kt * 32 + ((l >> 4) << 3) + i * 2;
    wsu[OFF_D0B + t] = pack2f(map89(dw0, u, k), map89(dw0, u, k + 1));
  } else if (id < 49152) {               // drift_w1
    int t = id - 40960;
    int i = t & 3, l = (t >> 2) & 63, wkt = t >> 8;
    int kt = wkt & 3, w = wkt >> 2;
    int u = w * 16 + (l & 15);
    int k = kt * 32 + ((l >> 4) << 3) + i * 2;
    wsu[OFF_D1B + t] = pack2f(dw1[u * 128 + k], dw1[u * 128 + k + 1]);
  } else if (id < 57344) {               // drift_w2
    int t = id - 49152;
    int i = t & 3, l = (t >> 2) & 63, wkt = t >> 8;
    int kt = wkt & 3, w = wkt >> 2;
    int u = w * 16 + (l & 15);
    int k = kt * 32 + ((l >> 4) << 3) + i * 2;
    wsu[OFF_D2B + t] = pack2f(dw2[u * 128 + k], dw2[u * 128 + k + 1]);
  } else if (id < 63488) {               // diff_w0 (89-in)
    int t = id - 57344;
    int i = t & 3, l = (t >> 2) & 63, wkt = t >> 8;
    int kt = wkt % 3, w = wkt / 3;
    int u = w * 16 + (l & 15);
    int k = kt * 32 + ((l >> 4) << 3) + i * 2;
    wsu[OFF_G0B + t] = pack2f(map89(gw0, u, k), map89(gw0, u, k + 1));
  } else if (id < 71680) {               // diff_w1
    int t = id - 63488;
    int i = t & 3, l = (t >> 2) & 63, wkt = t >> 8;
    int kt = wkt & 3, w = wkt >> 2;
    int u = w * 16 + (l & 15);
    int k = kt * 32 + ((l >> 4) << 3) + i * 2;
    wsu[OFF_G1B + t] = pack2f(gw1[u * 128 + k], gw1[u * 128 + k + 1]);
  } else if (id < 72704) {               // drift_w3 head (15 outs, pad 16)
    int t = id - 71680;
    int i = t & 3, l = (t >> 2) & 63, kt = t >> 8;
    int o = l & 15;
    int k = kt * 32 + ((l >> 4) << 3) + i * 2;
    float a = (o < 15) ? dw3[o * 128 + k]     : 0.f;
    float b = (o < 15) ? dw3[o * 128 + k + 1] : 0.f;
    wsu[OFF_W3B + t] = pack2f(a, b);
  } else if (id < 73728) {               // diff_w2 head
    int t = id - 72704;
    int i = t & 3, l = (t >> 2) & 63, kt = t >> 8;
    int o = l & 15;
    int k = kt * 32 + ((l >> 4) << 3) + i * 2;
    float a = (o < 15) ? gw2[o * 128 + k]     : 0.f;
    float b = (o < 15) ? gw2[o * 128 + k + 1] : 0.f;
    wsu[OFF_G2B + t] = pack2f(a, b);
  }
}

// MLP dual-slot phase: A-frags in LDS, B-frags in VGPRs.
template <int KT>
__device__ inline void mlp_pair(const _Float16* __restrict__ aA,
                                const FB* B0, const FB* B1,
                                float bias0, float bias1,
                                _Float16* __restrict__ outA,
                                int lm, int lq, int ubase) {
  f32x4 c0 = {0.f, 0.f, 0.f, 0.f}, c1 = {0.f, 0.f, 0.f, 0.f};
#pragma unroll
  for (int kt = 0; kt < KT; kt++) {
    half8 a = *(const half8*)(aA + ((kt * 4 + lq) * 16 + lm) * 8);
    c0 = __builtin_amdgcn_mfma_f32_16x16x32_f16(a, B0[kt].h, c0, 0, 0, 0);
    c1 = __builtin_amdgcn_mfma_f32_16x16x32_f16(a, B1[kt].h, c1, 0, 0, 0);
  }
  int u0 = ubase + lm, u1 = ubase + 16 + lm;
  int base0 = (u0 >> 3) * 128 + (u0 & 7);
  int base1 = (u1 >> 3) * 128 + (u1 & 7);
#pragma unroll
  for (int s = 0; s < 4; s++) {
    outA[base0 + (lq * 4 + s) * 8] = (_Float16)silu_f(c0[s] + bias0);
    outA[base1 + (lq * 4 + s) * 8] = (_Float16)silu_f(c1[s] + bias1);
  }
}

// Layer-0 with step-invariant ctx contribution pre-accumulated (C-operand).
__device__ inline void mlp_pair_pre(const _Float16* __restrict__ aA,
                                    const FB& B0k0, const FB& B1k0,
                                    f32x4 cc0, f32x4 cc1,
                                    float bias0, float bias1,
                                    _Float16* __restrict__ outA,
                                    int lm, int lq, int ubase) {
  half8 a = *(const half8*)(aA + ((0 * 4 + lq) * 16 + lm) * 8);  // sigma ktile
  f32x4 c0 = __builtin_amdgcn_mfma_f32_16x16x32_f16(a, B0k0.h, cc0, 0, 0, 0);
  f32x4 c1 = __builtin_amdgcn_mfma_f32_16x16x32_f16(a, B1k0.h, cc1, 0, 0, 0);
  int u0 = ubase + lm, u1 = ubase + 16 + lm;
  int base0 = (u0 >> 3) * 128 + (u0 & 7);
  int base1 = (u1 >> 3) * 128 + (u1 & 7);
#pragma unroll
  for (int s = 0; s < 4; s++) {
    outA[base0 + (lq * 4 + s) * 8] = (_Float16)silu_f(c0[s] + bias0);
    outA[base1 + (lq * 4 + s) * 8] = (_Float16)silu_f(c1[s] + bias1);
  }
}

__device__ inline f32x4 head4(const _Float16* __restrict__ aA, const FB* H,
                              int lm, int lq) {
  f32x4 c = {0.f, 0.f, 0.f, 0.f};
#pragma unroll
  for (int kt = 0; kt < 4; kt++) {
    half8 a = *(const half8*)(aA + ((kt * 4 + lq) * 16 + lm) * 8);
    c = __builtin_amdgcn_mfma_f32_16x16x32_f16(a, H[kt].h, c, 0, 0, 0);
  }
  return c;
}

// ---- 5x5 wave-parallel matmul via raw ds_bpermute (hoisted addresses) ----
__device__ inline float bpf(int addr, float v) {
  return __int_as_float(__builtin_amdgcn_ds_bpermute(addr, __float_as_int(v)));
}
__device__ inline float mm5b(int iA, int iB, float A, float B) {
  float c = 0.f;
#pragma unroll
  for (int k = 0; k < 5; k++)
    c = fmaf(bpf(iA + 4 * k, A), bpf(iB + 20 * k, B), c);
  return c;
}

#define NS_ITER do { \
  float P_  = mm5b(iA0, iB0, Zv, Yv); \
  float Tm_ = 1.5f * gdel - 0.5f * P_; \
  float Yn_ = mm5b(iA0, iB0, Yv, Tm_); \
  float Zn_ = mm5b(iA0, iB0, Tm_, Zv); \
  Yv = Yn_; Zv = Zn_; } while (0)

// ======================= fused GRU + SDE =======================
// grid 256 x 512; block owns 16 batch rows.
__global__ __launch_bounds__(512) void fused_kernel(
    const float* __restrict__ ctp, const float* __restrict__ dWp,
    const uint* __restrict__ wsu,
    const float* __restrict__ gbias, const float* __restrict__ gbn,
    const float* __restrict__ projb,
    const float* __restrict__ db0, const float* __restrict__ db1,
    const float* __restrict__ db2, const float* __restrict__ b3,
    const float* __restrict__ gb0, const float* __restrict__ gb1,
    const float* __restrict__ gb2, float* __restrict__ outp) {
  __shared__ __align__(16) _Float16 bigbuf[16384];           // 32KB: x2 / SDE bufs
  __shared__ __align__(16) _Float16 hf[2][4][4][16][8];      // 8KB dbuf h A-frags
  __shared__ float sig_s[16 * 28];
  __shared__ float coeff_s[256];
  __shared__ float coeff2_s[256];
  const int tid = threadIdx.x;
  const int rb = blockIdx.x * 16;
  uint* bigu = (uint*)bigbuf;

  // ---- stage symmetrized features as A-frags (x2 = bigbuf) ----
  for (int idx = tid; idx < T_STEPS * 16 * 16; idx += 512) {
    int k2 = idx & 15, r = (idx >> 4) & 15, t = idx >> 8;
    const float* base = ctp + ((rb + r) * T_STEPS + t) * 25;
    int k0 = 2 * k2;
    float v0 = 0.f, v1 = 0.f;
    if (k0 < 25)     { int i5 = k0 / 5,     j5 = k0 % 5;     v0 = 0.5f * (base[i5*5+j5] + base[j5*5+i5]); }
    if (k0 + 1 < 25) { int i5 = (k0+1) / 5, j5 = (k0+1) % 5; v1 = 0.5f * (base[i5*5+j5] + base[j5*5+i5]); }
    int q = k2 >> 2, jh = k2 & 3;
    bigu[((t * 4 + q) * 16 + r) * 4 + jh] = pack2f(v0, v1);
  }

  const int w = tid >> 6, l = tid & 63;
  const int lm = l & 15, lq = l >> 4;
  const int u = w * 16 + lm;
  const int ku = u >> 5, qu = (u >> 3) & 3, ju = u & 7;
  FB Bf[3][5];
  const uint4* wb4p = (const uint4*)(wsu + OFF_WB);
#pragma unroll
  for (int gi = 0; gi < 3; gi++)
#pragma unroll
    for (int kt = 0; kt < 5; kt++)
      Bf[gi][kt].u4 = wb4p[((w * 3 + gi) * 5 + kt) * 64 + l];
  const float br = gbias[u], bz = gbias[128 + u], bg = gbias[256 + u], bn = gbn[u];
  float hprev[4] = {0.f, 0.f, 0.f, 0.f};
  __syncthreads();

  // ---- GRU t-loop (1 barrier/step, x-part software-pipelined) ----
  f32x4 z4 = {0.f, 0.f, 0.f, 0.f};
  half8 axn = *(const half8*)(bigbuf + ((0 * 4 + lq) * 16 + lm) * 8);
  f32x4 pxr = __builtin_amdgcn_mfma_f32_16x16x32_f16(axn, Bf[0][0].h, z4, 0, 0, 0);
  f32x4 pxz = __builtin_amdgcn_mfma_f32_16x16x32_f16(axn, Bf[1][0].h, z4, 0, 0, 0);
  f32x4 pxg = __builtin_amdgcn_mfma_f32_16x16x32_f16(axn, Bf[2][0].h, z4, 0, 0, 0);
  for (int t = 0; t < T_STEPS; t++) {
    f32x4 cr = pxr, cz = pxz, cgv = pxg;
    f32x4 ch = {0.f, 0.f, 0.f, 0.f};
    if (t > 0) {
      const int p = t & 1;
#pragma unroll
      for (int kk = 0; kk < 4; kk++) {
        half8 ah = *(const half8*)(&hf[p][kk][lq][lm][0]);
        cr = __builtin_amdgcn_mfma_f32_16x16x32_f16(ah, Bf[0][1 + kk].h, cr, 0, 0, 0);
        cz = __builtin_amdgcn_mfma_f32_16x16x32_f16(ah, Bf[1][1 + kk].h, cz, 0, 0, 0);
        ch = __builtin_amdgcn_mfma_f32_16x16x32_f16(ah, Bf[2][1 + kk].h, ch, 0, 0, 0);
      }
    }
    if (t < T_STEPS - 1) {   // prefetch next step's x-part (independent of h)
      axn = *(const half8*)(bigbuf + (((t + 1) * 4 + lq) * 16 + lm) * 8);
      pxr = __builtin_amdgcn_mfma_f32_16x16x32_f16(axn, Bf[0][0].h, z4, 0, 0, 0);
      pxz = __builtin_amdgcn_mfma_f32_16x16x32_f16(axn, Bf[1][0].h, z4, 0, 0, 0);
      pxg = __builtin_amdgcn_mfma_f32_16x16x32_f16(axn, Bf[2][0].h, z4, 0, 0, 0);
    }
    const int wp = (t + 1) & 1;
#pragma unroll
    for (int s = 0; s < 4; s++) {
      float r = sigm(cr[s] + br);
      float z = sigm(cz[s] + bz);
      float g = tanh_fast(cgv[s] + bg + r * (ch[s] + bn));
      float hn = fmaf(z, hprev[s] - g, g);
      hprev[s] = hn;
      hf[wp][ku][qu][lq * 4 + s][ju] = (_Float16)hn;
    }
    __syncthreads();
  }

  // ---- SDE B-frag preload (registers), role-split ----
  const int role = w >> 2;                 // 0: drift (waves 0-3), 1: diff (4-7)
  const int wbq = w & 3;
  FB F0[2][3], F1[2][4], F2[2][4], Pf[4], Hf[4];
  {
    const uint4* p0 = (const uint4*)(wsu + (role ? OFF_G0B : OFF_D0B));
    const uint4* p1 = (const uint4*)(wsu + (role ? OFF_G1B : OFF_D1B));
    const uint4* p2 = (const uint4*)(wsu + (role ? OFF_G1B : OFF_D2B)); // diff: dummy
#pragma unroll
    for (int s = 0; s < 2; s++) {
      int slot = wbq * 2 + s;
#pragma unroll
      for (int kt = 0; kt < 3; kt++) F0[s][kt].u4 = p0[(slot * 3 + kt) * 64 + l];
#pragma unroll
      for (int kt = 0; kt < 4; kt++) {
        F1[s][kt].u4 = p1[(slot * 4 + kt) * 64 + l];
        F2[s][kt].u4 = p2[(slot * 4 + kt) * 64 + l];
      }
    }
  }
  if (w < 4) {
#pragma unroll
    for (int kt = 0; kt < 4; kt++)
      Pf[kt].u4 = ((const uint4*)(wsu + OFF_PJB))[(w * 4 + kt) * 64 + l];
  }
  if (w == 0) {
#pragma unroll
    for (int kt = 0; kt < 4; kt++)
      Hf[kt].u4 = ((const uint4*)(wsu + OFF_W3B))[kt * 64 + l];
  } else if (w == 4) {
#pragma unroll
    for (int kt = 0; kt < 4; kt++)
      Hf[kt].u4 = ((const uint4*)(wsu + OFF_G2B))[kt * 64 + l];
  }
  float b0s[2], b1s[2], b2s[2];
#pragma unroll
  for (int s = 0; s < 2; s++) {
    int us = wbq * 32 + s * 16 + lm;
    b0s[s] = role ? gb0[us] : db0[us];
    b1s[s] = role ? gb1[us] : db1[us];
    b2s[s] = role ? 0.f : db2[us];
  }
  const int oc = (lm < 15) ? lm : 0;
  const float hb = (w == 0) ? b3[oc] : ((w == 4) ? gb2[oc] : 0.f);

  // prefetch ALL steps' dW (wave 4 only) so no vmem is outstanding at barriers
  float dwa[5][4];
  if (w == 4) {
#pragma unroll
    for (int st = 0; st < 5; st++)
#pragma unroll
      for (int s = 0; s < 4; s++)
        dwa[st][s] = dWp[((rb + lq * 4 + s) * 5 + st) * 15 + oc];
  }

  _Float16* inpA = bigbuf;          // 3 ktiles (k: 0-24 sigma | pad | 32-95 ctx)
  _Float16* bufA = bigbuf + 1536;   // drift d0 out / d2 out
  _Float16* bufB = bigbuf + 3584;   // diff g0 out
  _Float16* bufC = bigbuf + 5632;   // drift d1 out
  _Float16* bufD = bigbuf + 7680;   // diff g1 out

  // proj via MFMA (waves 0-3): ctx -> inpA ctx part
  if (w < 4) {
    f32x4 c = {0.f, 0.f, 0.f, 0.f};
#pragma unroll
    for (int kt = 0; kt < 4; kt++) {
      half8 a = *(const half8*)(&hf[0][kt][lq][lm][0]);
      c = __builtin_amdgcn_mfma_f32_16x16x32_f16(a, Pf[kt].h, c, 0, 0, 0);
    }
    const float pbv = projb[u];
    int kk = 32 + u, base = (kk >> 3) * 128 + (kk & 7);
#pragma unroll
    for (int s = 0; s < 4; s++)
      inpA[base + (lq * 4 + s) * 8] = (_Float16)(c[s] + pbv);
  }
  // sigma init + pad
  for (int idx = tid; idx < 400; idx += 512) {
    int e = idx / 25, k = idx % 25;
    int i5 = k / 5, j5 = k % 5;
    const float* base = ctp + ((rb + e) * T_STEPS + 31) * 25;
    float v = 0.5f * (base[i5 * 5 + j5] + base[j5 * 5 + i5]);
    sig_s[e * 28 + k] = v;
    inpA[(k >> 3) * 128 + e * 8 + (k & 7)] = (_Float16)v;
  }
  if (tid < 112) {
    int e = tid / 7, p = 25 + tid % 7;
    inpA[(p >> 3) * 128 + e * 8 + (p & 7)] = (_Float16)0.f;
  }
  // geometry lane constants
  const int ge = tid >> 5, glane = tid & 31;
  const int gli = (glane < 25) ? glane : 0;
  const int gii = gli / 5, gjj = gli % 5;
  const float gdel = (gii == gjj) ? 1.f : 0.f;
  const int gbase = (l & 32) << 2;
  const int iA0 = gbase + gii * 20;
  const int iB0 = gbase + gjj * 4;
  const int iT0 = gbase + (gjj * 5 + gii) * 4;
  __syncthreads();

  // step-invariant ctx contribution to layer0 (ktiles 1-2), both slots
  f32x4 cc0 = {0.f, 0.f, 0.f, 0.f}, cc1 = {0.f, 0.f, 0.f, 0.f};
#pragma unroll
  for (int kt = 1; kt < 3; kt++) {
    half8 a = *(const half8*)(inpA + ((kt * 4 + lq) * 16 + lm) * 8);
    cc0 = __builtin_amdgcn_mfma_f32_16x16x32_f16(a, F0[0][kt].h, cc0, 0, 0, 0);
    cc1 = __builtin_amdgcn_mfma_f32_16x16x32_f16(a, F0[1][kt].h, cc1, 0, 0, 0);
  }

  // ---- SDE step loop: 5 barriers/step; sqrt = cheb4 + NS1 + NS2 ----
  for (int st = 0; st < 5; st++) {
    float S = sig_s[ge * 28 + gli];
    float tr = 0.f;
#pragma unroll
    for (int d = 0; d < 5; d++) tr += bpf(gbase + 24 * d, S);
    const float That = S * (2.298851f / tr) - 1.068966f * gdel;
    float Yv, Zv;
    // p1: d0 || g0 (sigma ktile only; ctx pre-accumulated) + cheb4
    mlp_pair_pre(inpA, F0[0][0], F0[1][0], cc0, cc1, b0s[0], b0s[1],
                 role ? bufB : bufA, lm, lq, wbq * 32);
    {
      float T2 = mm5b(iA0, iB0, That, That);
      float X  = -1.13859f * That + 0.9901f * T2;
      float Zp = mm5b(iA0, iB0, T2, X)
               + 1.03702f * gdel - 0.21179f * That + 0.09756f * T2;
      Zv = Zp;
      float TZ = mm5b(iA0, iB0, That, Zp);
      Yv = 0.87f * TZ + 0.93f * Zp;
    }
    __syncthreads();
    // p2: d1 || g1  (+ NS1)
    mlp_pair<4>(role ? bufB : bufA, F1[0], F1[1], b1s[0], b1s[1],
                role ? bufD : bufC, lm, lq, wbq * 32);
    NS_ITER;
    __syncthreads();
    // p3: d2 || diff-head  (+ NS2)
    if (!role) {
      mlp_pair<4>(bufC, F2[0], F2[1], b2s[0], b2s[1], bufA, lm, lq, wbq * 32);
    } else if (w == 4) {
      f32x4 c = head4(bufD, Hf, lm, lq);
      if (lm < 15) {
#pragma unroll
        for (int s = 0; s < 4; s++) {
          float acc = c[s] + hb;
          float sp = (acc > 20.f) ? acc : __logf(1.f + __expf(acc));
          coeff2_s[(lq * 4 + s) * 16 + lm] = sp * dwa[st][s];
        }
      }
    }
    NS_ITER;
    __syncthreads();
    // p4: drift head; finalize L
    if (w == 0) {
      f32x4 c = head4(bufA, Hf, lm, lq);
      if (lm < 15) {
#pragma unroll
        for (int s = 0; s < 4; s++)
          coeff_s[(lq * 4 + s) * 16 + lm] = 0.2f * (c[s] + hb);
      }
    }
    float L = Yv * sqrtf(0.5f * tr);
    __syncthreads();
    // p5: tangent build + expm (deg-4 powers) + exp-map + write
    {
      float av;
      if (gii == gjj) av = coeff_s[ge * 16 + gii] + coeff2_s[ge * 16 + gii];
      else {
        int p = gii < gjj ? gii : gjj, qq = gii < gjj ? gjj : gii;
        int i5 = 5 + (p * (9 - p)) / 2 + (qq - p - 1);
        av = (coeff_s[ge * 16 + i5] + coeff2_s[ge * 16 + i5]) * 0.70710678f;
      }
      float a2 = mm5b(iA0, iB0, av, av);
      float X2 = 0.5f * gdel + av * 0.16666667f + a2 * 0.04166667f;
      float M = gdel + av + mm5b(iA0, iB0, a2, X2);
      float P2 = mm5b(iA0, iB0, L, M);
      float S2 = mm5b(iA0, iB0, P2, L);
      S2 = 0.5f * (S2 + bpf(iT0, S2));
      if (glane < 25) {
        sig_s[ge * 28 + gli] = S2;
        inpA[(gli >> 3) * 128 + ge * 8 + (gli & 7)] = (_Float16)S2;
      }
    }
    __syncthreads();
  }

  for (int idx = tid; idx < 400; idx += 512) {
    int e = idx / 25, k = idx % 25;
    outp[(rb + e) * 25 + k] = sig_s[e * 28 + k];
  }
}

extern "C" void kernel_launch(void* const* d_in, const int* in_sizes, int n_in,
                              void* d_out, int out_size, void* d_ws, size_t ws_size,
                              hipStream_t stream) {
  const float* ctp = (const float*)d_in[0];
  const float* dWp = (const float*)d_in[1];
  const float* wih = (const float*)d_in[2];
  const float* whh = (const float*)d_in[3];
  const float* gb  = (const float*)d_in[4];
  const float* gbn = (const float*)d_in[5];
  const float* pw  = (const float*)d_in[6];
  const float* pb  = (const float*)d_in[7];
  const float* dw0 = (const float*)d_in[8];
  const float* db0 = (const float*)d_in[9];
  const float* dw1 = (const float*)d_in[10];
  const float* db1 = (const float*)d_in[11];
  const float* dw2 = (const float*)d_in[12];
  const float* db2 = (const float*)d_in[13];
  const float* dw3 = (const float*)d_in[14];
  const float* db3 = (const float*)d_in[15];
  const float* gw0 = (const float*)d_in[16];
  const float* gb0 = (const float*)d_in[17];
  const float* gw1 = (const float*)d_in[18];
  const float* gb1 = (const float*)d_in[19];
  const float* gw2 = (const float*)d_in[20];
  const float* gb2 = (const float*)d_in[21];
  uint* wsu = (uint*)d_ws;

  hipLaunchKernelGGL(prep_kernel, dim3(288), dim3(256), 0, stream,
                     wih, whh, pw, dw0, dw1, dw2, gw0, gw1, dw3, gw2, wsu);
  hipLaunchKernelGGL(fused_kernel, dim3(256), dim3(512), 0, stream,
                     ctp, dWp, wsu, gb, gbn, pb,
                     db0, db1, db2, db3, gb0, gb1, gb2, (float*)d_out);
}